// Round 10
// baseline (389.083 us; speedup 1.0000x reference)
//
#include <hip/hip_runtime.h>
#include <hip/hip_bf16.h>

#define TDIM 2048
#define DDIM 768
#define IDIM 2048
#define NEXP 8

typedef __bf16 v8bf __attribute__((ext_vector_type(8)));
typedef __bf16 v4bf __attribute__((ext_vector_type(4)));
typedef float v4f __attribute__((ext_vector_type(4)));
typedef int   v4i __attribute__((ext_vector_type(4)));
typedef float v4ff __attribute__((ext_vector_type(4)));

#define MFMA_B16(A,B,C) __builtin_amdgcn_mfma_f32_16x16x32_bf16(A,B,C,0,0,0)

typedef __attribute__((address_space(1))) const unsigned int* gas_t;
typedef __attribute__((address_space(3))) unsigned int* las_t;

__device__ __forceinline__ void gload16(const void* g, void* l) {
  __builtin_amdgcn_global_load_lds((gas_t)g, (las_t)l, 16, 0, 0);
}

// int32 {-1,0,1} or fp32-bits -> 4x bf16 (isint is block-uniform)
__device__ __forceinline__ v4bf conv4(v4i r, int isint) {
  v4bf v;
  if (isint) {
    v[0] = (__bf16)(float)r[0]; v[1] = (__bf16)(float)r[1];
    v[2] = (__bf16)(float)r[2]; v[3] = (__bf16)(float)r[3];
  } else {
    v[0] = (__bf16)__int_as_float(r[0]); v[1] = (__bf16)__int_as_float(r[1]);
    v[2] = (__bf16)__int_as_float(r[2]); v[3] = (__bf16)__int_as_float(r[3]);
  }
  return v;
}

// ================= prep: router + x-pack =================
// blocks [0,512): router, 4 tokens/block (1/wave); wt premultiplied by sd[e]
// blocks [512,768): x fp32 -> bf16 (linear), 8 rows/block
__global__ __launch_bounds__(256)
void prep_kernel(const float* __restrict__ x, const float* __restrict__ rw,
                 const float* __restrict__ es, __hip_bfloat16* __restrict__ xb,
                 int* __restrict__ cnt, int* __restrict__ lists, float* __restrict__ wt)
{
  const int b = blockIdx.x;
  const int tid = threadIdx.x;

  if (b < 512) {  // router
    const int t = b * 4 + (tid >> 6);
    const int lane = tid & 63;
    const float* xp = x + (size_t)t * DDIM;
    float4 xv0 = *(const float4*)(xp + lane * 4);
    float4 xv1 = *(const float4*)(xp + 256 + lane * 4);
    float4 xv2 = *(const float4*)(xp + 512 + lane * 4);
    float logit[NEXP];
#pragma unroll
    for (int e = 0; e < NEXP; ++e) {
      const float* w = rw + (size_t)e * DDIM;
      float4 w0 = *(const float4*)(w + lane * 4);
      float4 w1 = *(const float4*)(w + 256 + lane * 4);
      float4 w2 = *(const float4*)(w + 512 + lane * 4);
      float p = xv0.x * w0.x + xv0.y * w0.y + xv0.z * w0.z + xv0.w * w0.w
              + xv1.x * w1.x + xv1.y * w1.y + xv1.z * w1.z + xv1.w * w1.w
              + xv2.x * w2.x + xv2.y * w2.y + xv2.z * w2.z + xv2.w * w2.w;
#pragma unroll
      for (int off = 32; off > 0; off >>= 1) p += __shfl_down(p, off, 64);
      logit[e] = p;
    }
    if (lane == 0) {
      float m = logit[0];
#pragma unroll
      for (int e = 1; e < NEXP; ++e) m = fmaxf(m, logit[e]);
      float pr[NEXP];
#pragma unroll
      for (int e = 0; e < NEXP; ++e) pr[e] = expf(logit[e] - m);
      int i0 = 0; float v0 = pr[0];
#pragma unroll
      for (int e = 1; e < NEXP; ++e) if (pr[e] > v0) { v0 = pr[e]; i0 = e; }
      int i1 = -1; float v1 = -1.f;
#pragma unroll
      for (int e = 0; e < NEXP; ++e) if (e != i0 && pr[e] > v1) { v1 = pr[e]; i1 = e; }
      float inv = 1.f / (v0 + v1);
      int p0 = atomicAdd(&cnt[i0], 1);
      lists[i0 * TDIM + p0] = t * 2;
      wt[t * 2] = v0 * inv * es[i0 * 3 + 2];
      int p1 = atomicAdd(&cnt[i1], 1);
      lists[i1 * TDIM + p1] = t * 2 + 1;
      wt[t * 2 + 1] = v1 * inv * es[i1 * 3 + 2];
    }
    return;
  }

  // x pack
  const int lc = tid & 31;
  const int rowloc = tid >> 5;
  const int row = (b - 512) * 8 + rowloc;
  const float* sp = x + (size_t)row * DDIM;
  __hip_bfloat16* dp = xb + (size_t)row * DDIM;
  v4ff r[6];
#pragma unroll
  for (int i = 0; i < 6; ++i) r[i] = *(const v4ff*)(sp + (lc + i * 32) * 4);
#pragma unroll
  for (int i = 0; i < 6; ++i) {
    v4bf v;
    v[0] = (__bf16)r[i][0]; v[1] = (__bf16)r[i][1];
    v[2] = (__bf16)r[i][2]; v[3] = (__bf16)r[i][3];
    *(v4bf*)(dp + (lc + i * 32) * 4) = v;
  }
}

// ================= fused gate+up GEMM, 128x128 tile, inline dequant =================
// blocks [0,4096): experts (e=b>>9, tm=(b>>5)&15, tn=b&31), gathered rows
// blocks [4096,4608): shared expert, dense rows (h rows 4096+t)
// B built in LDS from raw int32/fp32 sources (reg-stage + swizzled ds_write);
// combined N=4096 interleaves gate/up at 16-row granularity -> in-register silu.
__global__ __launch_bounds__(256)
void gu_gemm_kernel(const __hip_bfloat16* __restrict__ xb,
                    const int* __restrict__ qg, const int* __restrict__ qu,
                    const float* __restrict__ sgw, const float* __restrict__ suw,
                    const float* __restrict__ es,
                    const int* __restrict__ cnt, const int* __restrict__ lists,
                    __hip_bfloat16* __restrict__ h)
{
  const int b = blockIdx.x;
  int tm, tn, count, isint;
  const char *srcG, *srcU;
  const int* listE = nullptr;
  float sgc, suc;
  if (b < 4096) {
    const int e = b >> 9; tm = (b >> 5) & 15; tn = b & 31;
    count = cnt[e];
    if (tm * 128 >= count) return;
    srcG = (const char*)(qg + (size_t)e * IDIM * DDIM);
    srcU = (const char*)(qu + (size_t)e * IDIM * DDIM);
    listE = lists + e * TDIM;
    sgc = es[e * 3 + 0]; suc = es[e * 3 + 1];
    isint = 1;
  } else {
    const int b2 = b - 4096; tm = b2 >> 5; tn = b2 & 31;
    count = TDIM;
    srcG = (const char*)sgw; srcU = (const char*)suw;
    sgc = 1.f; suc = 1.f; isint = 0;
  }

  __shared__ __align__(16) char As[2][16384];
  __shared__ __align__(16) char Bs[16384];

  const int tid = threadIdx.x;
  const int lane = tid & 63;
  const int wid = tid >> 6;
  const int wr = wid >> 1, wc = wid & 1;
  const int lr16 = lane & 15, hk = lane >> 4;

  // A gather pointers (pre-swizzled global col, linear LDS dest)
  const int cA = (((lane & 7) ^ (lane >> 3)) << 4);
  const char* aptr[4];
#pragma unroll
  for (int p = 0; p < 4; ++p) {
    const int row = p * 32 + wid * 8 + (lane >> 3);
    const int rg = tm * 128 + row;
    int tok;
    if (listE) { const int idx = rg < count ? rg : count - 1; tok = listE[idx] >> 1; }
    else tok = rg;
    aptr[p] = (const char*)xb + (size_t)tok * (DDIM * 2) + cA;
  }

  // B staging: thread owns (rowb = tid>>4, lanec = tid&15); pass p -> tile row rowb+16p.
  // combined row rg = tn*128 + rowb + 16p: tensor = p&1 (gate/up), srcrow = (tn*4 + p/2)*16 + rowb
  const int lanec = tid & 15;
  const int rowb = tid >> 4;
  const char* bq[8];
  int dsoff[8];
#pragma unroll
  for (int p = 0; p < 8; ++p) {
    const int srcrow = (tn * 4 + (p >> 1)) * 16 + rowb;
    const char* base = (p & 1) ? srcU : srcG;
    bq[p] = base + ((size_t)srcrow * DDIM + lanec * 4) * 4;
    const int r = rowb + 16 * p;
    dsoff[p] = r * 128 + ((lanec * 8) ^ ((rowb & 7) << 4));
  }

  v4f acc[4][4] = {};
  v4i braw[8];
  v4bf bconv[8];

  // prologue: A(0) -> As[0]; B(0) -> regs -> converted
#pragma unroll
  for (int p = 0; p < 4; ++p) gload16(aptr[p], As[0] + wid * 1024 + p * 4096);
#pragma unroll
  for (int p = 0; p < 8; ++p) braw[p] = *(const v4i*)(bq[p]);
#pragma unroll
  for (int p = 0; p < 8; ++p) bconv[p] = conv4(braw[p], isint);

  for (int kt = 0; kt < 12; ++kt) {
    const int cur = kt & 1;
#pragma unroll
    for (int p = 0; p < 8; ++p) *(v4bf*)(Bs + dsoff[p]) = bconv[p];
    __syncthreads();                       // A(kt) landed; Bs(kt) written
    if (kt + 1 < 12) {
#pragma unroll
      for (int p = 0; p < 4; ++p) gload16(aptr[p] + (kt + 1) * 128, As[cur ^ 1] + wid * 1024 + p * 4096);
#pragma unroll
      for (int p = 0; p < 8; ++p) braw[p] = *(const v4i*)(bq[p] + (kt + 1) * 256);
    }
#pragma unroll
    for (int ks = 0; ks < 2; ++ks) {
      const int colb = ks * 64 + hk * 16;
      v8bf fa[4], fb[4];
#pragma unroll
      for (int m = 0; m < 4; ++m) {
        const int r = wr * 64 + m * 16 + lr16;
        fa[m] = *(const v8bf*)(As[cur] + r * 128 + (colb ^ ((r & 7) << 4)));
      }
#pragma unroll
      for (int n = 0; n < 4; ++n) {
        const int r = wc * 64 + n * 16 + lr16;
        fb[n] = *(const v8bf*)(Bs + r * 128 + (colb ^ ((r & 7) << 4)));
      }
#pragma unroll
      for (int n = 0; n < 4; ++n)
#pragma unroll
        for (int m = 0; m < 4; ++m) acc[m][n] = MFMA_B16(fa[m], fb[n], acc[m][n]);
    }
    __syncthreads();                       // Bs consumed; A/B(kt+1) drain (issued pre-MFMA)
    if (kt + 1 < 12) {
#pragma unroll
      for (int p = 0; p < 8; ++p) bconv[p] = conv4(braw[p], isint);
    }
  }

  // epilogue: pairs (2p,2p+1) = (g,u) for i = (tn*4 + wc*2 + p)*16 + lr16
#pragma unroll
  for (int m = 0; m < 4; ++m) {
#pragma unroll
    for (int j = 0; j < 4; ++j) {
      const int rl = wr * 64 + m * 16 + hk * 4 + j;
      const int rg = tm * 128 + rl;
      if (rg >= count) continue;
      const size_t drow = listE ? (size_t)listE[rg] : (size_t)(4096 + rg);
      __hip_bfloat16* dh = h + drow * IDIM + (tn * 4 + wc * 2) * 16 + lr16;
#pragma unroll
      for (int p = 0; p < 2; ++p) {
        const float g = acc[m][2 * p][j] * sgc;
        const float u = acc[m][2 * p + 1][j] * suc;
        dh[p * 16] = __float2bfloat16(g / (1.f + __expf(-g)) * u);
      }
    }
  }
}

// ================= fused down GEMM, 128x128 tile, K=2048, inline dequant =================
// blocks [0,768): experts (e=b/96, tm=(b%96)/6, tn=b%6), A = h[slot]; out rows = slot
// blocks [768,864): shared expert, A = h[4096+t]; out rows = 4096+t
// Writes fp32 partials (no atomics); combine sums slot0+slot1+shared.
__global__ __launch_bounds__(256)
void down_gemm_kernel(const __hip_bfloat16* __restrict__ h,
                      const int* __restrict__ qd, const float* __restrict__ sdw,
                      const float* __restrict__ wt,
                      const int* __restrict__ cnt, const int* __restrict__ lists,
                      float* __restrict__ part)
{
  const int b = blockIdx.x;
  int tm, tn, count, isint;
  const char* srcB;
  const int* listE = nullptr;
  if (b < 768) {
    const int e = b / 96; const int r = b % 96; tm = r / 6; tn = r % 6;
    count = cnt[e];
    if (tm * 128 >= count) return;
    srcB = (const char*)(qd + (size_t)e * DDIM * IDIM);
    listE = lists + e * TDIM;
    isint = 1;
  } else {
    const int r = b - 768; tm = r / 6; tn = r % 6;
    count = TDIM;
    srcB = (const char*)sdw;
    isint = 0;
  }

  __shared__ __align__(16) char As[2][16384];
  __shared__ __align__(16) char Bs[16384];

  const int tid = threadIdx.x;
  const int lane = tid & 63;
  const int wid = tid >> 6;
  const int wr = wid >> 1, wc = wid & 1;
  const int lr16 = lane & 15, hk = lane >> 4;

  const int cA = (((lane & 7) ^ (lane >> 3)) << 4);
  const char* aptr[4];
#pragma unroll
  for (int p = 0; p < 4; ++p) {
    const int row = p * 32 + wid * 8 + (lane >> 3);
    const int rg = tm * 128 + row;
    int srow;
    if (listE) { const int idx = rg < count ? rg : count - 1; srow = listE[idx]; }
    else srow = 4096 + rg;
    aptr[p] = (const char*)h + (size_t)srow * (IDIM * 2) + cA;
  }

  const int lanec = tid & 15;
  const int rowb = tid >> 4;
  const char* bq[8];
  int dsoff[8];
#pragma unroll
  for (int p = 0; p < 8; ++p) {
    const int srcrow = tn * 128 + rowb + 16 * p;
    bq[p] = srcB + ((size_t)srcrow * IDIM + lanec * 4) * 4;
    const int r = rowb + 16 * p;
    dsoff[p] = r * 128 + ((lanec * 8) ^ ((rowb & 7) << 4));
  }

  v4f acc[4][4] = {};
  v4i braw[8];
  v4bf bconv[8];

#pragma unroll
  for (int p = 0; p < 4; ++p) gload16(aptr[p], As[0] + wid * 1024 + p * 4096);
#pragma unroll
  for (int p = 0; p < 8; ++p) braw[p] = *(const v4i*)(bq[p]);
#pragma unroll
  for (int p = 0; p < 8; ++p) bconv[p] = conv4(braw[p], isint);

  for (int kt = 0; kt < 32; ++kt) {
    const int cur = kt & 1;
#pragma unroll
    for (int p = 0; p < 8; ++p) *(v4bf*)(Bs + dsoff[p]) = bconv[p];
    __syncthreads();
    if (kt + 1 < 32) {
#pragma unroll
      for (int p = 0; p < 4; ++p) gload16(aptr[p] + (kt + 1) * 128, As[cur ^ 1] + wid * 1024 + p * 4096);
#pragma unroll
      for (int p = 0; p < 8; ++p) braw[p] = *(const v4i*)(bq[p] + (kt + 1) * 256);
    }
#pragma unroll
    for (int ks = 0; ks < 2; ++ks) {
      const int colb = ks * 64 + hk * 16;
      v8bf fa[4], fb[4];
#pragma unroll
      for (int m = 0; m < 4; ++m) {
        const int r = wr * 64 + m * 16 + lr16;
        fa[m] = *(const v8bf*)(As[cur] + r * 128 + (colb ^ ((r & 7) << 4)));
      }
#pragma unroll
      for (int n = 0; n < 4; ++n) {
        const int r = wc * 64 + n * 16 + lr16;
        fb[n] = *(const v8bf*)(Bs + r * 128 + (colb ^ ((r & 7) << 4)));
      }
#pragma unroll
      for (int n = 0; n < 4; ++n)
#pragma unroll
        for (int m = 0; m < 4; ++m) acc[m][n] = MFMA_B16(fa[m], fb[n], acc[m][n]);
    }
    __syncthreads();
    if (kt + 1 < 32) {
#pragma unroll
      for (int p = 0; p < 8; ++p) bconv[p] = conv4(braw[p], isint);
    }
  }

#pragma unroll
  for (int m = 0; m < 4; ++m) {
#pragma unroll
    for (int j = 0; j < 4; ++j) {
      const int rl = wr * 64 + m * 16 + hk * 4 + j;
      const int rg = tm * 128 + rl;
      if (rg >= count) continue;
      int orow; float w;
      if (listE) { const int slot = listE[rg]; orow = slot; w = wt[slot]; }  // wt premul sd
      else { orow = 4096 + rg; w = 1.f; }
      float* dst = part + (size_t)orow * DDIM + tn * 128 + wc * 64 + lr16;
#pragma unroll
      for (int n = 0; n < 4; ++n) dst[n * 16] = acc[m][n][j] * w;
    }
  }
}

// ================= combine: out[t] = part[2t] + part[2t+1] + part[4096+t] =================
__global__ __launch_bounds__(256)
void combine_kernel(const float* __restrict__ part, float* __restrict__ out)
{
  const int i4 = blockIdx.x * 256 + threadIdx.x;
  const int i0 = i4 * 4;
  const int t = i0 / DDIM;
  const int d = i0 - t * DDIM;
  float4 a = *(const float4*)(part + (size_t)(2 * t) * DDIM + d);
  float4 bb = *(const float4*)(part + (size_t)(2 * t + 1) * DDIM + d);
  float4 c = *(const float4*)(part + (size_t)(4096 + t) * DDIM + d);
  float4 r;
  r.x = a.x + bb.x + c.x;
  r.y = a.y + bb.y + c.y;
  r.z = a.z + bb.z + c.z;
  r.w = a.w + bb.w + c.w;
  *(float4*)(out + i0) = r;
}

extern "C" void kernel_launch(void* const* d_in, const int* in_sizes, int n_in,
                              void* d_out, int out_size, void* d_ws, size_t ws_size,
                              hipStream_t stream)
{
  const float* x   = (const float*)d_in[0];
  const float* rw  = (const float*)d_in[1];
  const float* swg = (const float*)d_in[2];
  const float* swu = (const float*)d_in[3];
  const float* swd = (const float*)d_in[4];
  const int*   qg  = (const int*)d_in[5];
  const int*   qu  = (const int*)d_in[6];
  const int*   qd  = (const int*)d_in[7];
  const float* es  = (const float*)d_in[8];
  float* out = (float*)d_out;

  char* ws = (char*)d_ws;
  size_t off = 0;
  auto alloc = [&](size_t bytes) { void* p = ws + off; off = (off + bytes + 255) & ~(size_t)255; return p; };
  // ws usage ~= 47 MB
  int*   cnt   = (int*)alloc(NEXP * 4);
  int*   lists = (int*)alloc((size_t)NEXP * TDIM * 4);
  float* wt    = (float*)alloc((size_t)2 * TDIM * 4);
  __hip_bfloat16* xb = (__hip_bfloat16*)alloc((size_t)TDIM * DDIM * 2);
  __hip_bfloat16* h  = (__hip_bfloat16*)alloc((size_t)(4096 + TDIM) * IDIM * 2);
  float* part = (float*)alloc((size_t)(4096 + TDIM) * DDIM * 4);

  hipMemsetAsync(cnt, 0, NEXP * 4, stream);

  prep_kernel<<<768, 256, 0, stream>>>(x, rw, es, xb, cnt, lists, wt);
  gu_gemm_kernel<<<4096 + 512, 256, 0, stream>>>(xb, qg, qu, swg, swu, es, cnt, lists, h);
  down_gemm_kernel<<<768 + 96, 256, 0, stream>>>(h, qd, swd, wt, cnt, lists, part);
  combine_kernel<<<(TDIM * DDIM / 4) / 256, 256, 0, stream>>>(part, out);
}

// Round 11
// 343.825 us; speedup vs baseline: 1.1316x; 1.1316x over previous
//
#include <hip/hip_runtime.h>
#include <hip/hip_bf16.h>

#define TDIM 2048
#define DDIM 768
#define IDIM 2048
#define NEXP 8

typedef __bf16 v8bf __attribute__((ext_vector_type(8)));
typedef __bf16 v4bf __attribute__((ext_vector_type(4)));
typedef float v4f __attribute__((ext_vector_type(4)));
typedef int   v4i __attribute__((ext_vector_type(4)));
typedef float v4ff __attribute__((ext_vector_type(4)));

#define MFMA_B16(A,B,C) __builtin_amdgcn_mfma_f32_16x16x32_bf16(A,B,C,0,0,0)

typedef __attribute__((address_space(1))) const unsigned int* gas_t;
typedef __attribute__((address_space(3))) unsigned int* las_t;

__device__ __forceinline__ void gload16(const void* g, void* l) {
  __builtin_amdgcn_global_load_lds((gas_t)g, (las_t)l, 16, 0, 0);
}

__device__ __forceinline__ v4bf cvt4_i(v4i a) {
  v4bf v;
  v[0] = (__bf16)(float)a[0]; v[1] = (__bf16)(float)a[1];
  v[2] = (__bf16)(float)a[2]; v[3] = (__bf16)(float)a[3];
  return v;
}
__device__ __forceinline__ v4bf cvt4_f(v4ff a) {
  v4bf v;
  v[0] = (__bf16)a[0]; v[1] = (__bf16)a[1]; v[2] = (__bf16)a[2]; v[3] = (__bf16)a[3];
  return v;
}

// ================= merged router + x-pack + LINEAR weight pack =================
// Pack v4: fully linear streams both sides (m13 copy pattern). Outputs are plain
// ROW-MAJOR bf16 tensors; the GEMMs handle LDS swizzle via per-lane pre-swizzled
// global columns (the proven A-path idiom). gate/up keep the 16-row interleave
// into a combined [4096][768] tensor (dst runs are 16-row contiguous -> linear).
// blocks [0,512):      router (wt premultiplied by sd[e])
// blocks [512,768):    x fp32 -> bf16, 8 rows/block
// blocks [768,4864):   expert gate/up: e=pb>>9, T=(pb>>8)&1, r8=pb&255
// blocks [4864,5376):  shared gate/up: T=sb>>8, r8=sb&255
// blocks [5376,6144):  expert down: e=pb/96, r8=pb%96 (row-major copy)
// blocks [6144,6240):  shared down
__global__ __launch_bounds__(256)
void pack_all_kernel(const int* __restrict__ qg, const int* __restrict__ qu,
                     const int* __restrict__ qd,
                     const float* __restrict__ sg, const float* __restrict__ su,
                     const float* __restrict__ sd, const float* __restrict__ x,
                     const float* __restrict__ rw, const float* __restrict__ es,
                     __hip_bfloat16* __restrict__ wgub, __hip_bfloat16* __restrict__ sgub,
                     __hip_bfloat16* __restrict__ wdb,  __hip_bfloat16* __restrict__ sdb,
                     __hip_bfloat16* __restrict__ xb,
                     int* __restrict__ cnt, int* __restrict__ lists, float* __restrict__ wt)
{
  const int b = blockIdx.x;
  const int tid = threadIdx.x;

  if (b < 512) {  // ---------------- router ----------------
    const int t = b * 4 + (tid >> 6);
    const int lane = tid & 63;
    const float* xp = x + (size_t)t * DDIM;
    float4 xv0 = *(const float4*)(xp + lane * 4);
    float4 xv1 = *(const float4*)(xp + 256 + lane * 4);
    float4 xv2 = *(const float4*)(xp + 512 + lane * 4);
    float logit[NEXP];
#pragma unroll
    for (int e = 0; e < NEXP; ++e) {
      const float* w = rw + (size_t)e * DDIM;
      float4 w0 = *(const float4*)(w + lane * 4);
      float4 w1 = *(const float4*)(w + 256 + lane * 4);
      float4 w2 = *(const float4*)(w + 512 + lane * 4);
      float p = xv0.x * w0.x + xv0.y * w0.y + xv0.z * w0.z + xv0.w * w0.w
              + xv1.x * w1.x + xv1.y * w1.y + xv1.z * w1.z + xv1.w * w1.w
              + xv2.x * w2.x + xv2.y * w2.y + xv2.z * w2.z + xv2.w * w2.w;
#pragma unroll
      for (int off = 32; off > 0; off >>= 1) p += __shfl_down(p, off, 64);
      logit[e] = p;
    }
    if (lane == 0) {
      float m = logit[0];
#pragma unroll
      for (int e = 1; e < NEXP; ++e) m = fmaxf(m, logit[e]);
      float pr[NEXP];
#pragma unroll
      for (int e = 0; e < NEXP; ++e) pr[e] = expf(logit[e] - m);
      int i0 = 0; float v0 = pr[0];
#pragma unroll
      for (int e = 1; e < NEXP; ++e) if (pr[e] > v0) { v0 = pr[e]; i0 = e; }
      int i1 = -1; float v1 = -1.f;
#pragma unroll
      for (int e = 0; e < NEXP; ++e) if (e != i0 && pr[e] > v1) { v1 = pr[e]; i1 = e; }
      float inv = 1.f / (v0 + v1);
      int p0 = atomicAdd(&cnt[i0], 1);
      lists[i0 * TDIM + p0] = t * 2;       // slot = t*2 + k
      wt[t * 2] = v0 * inv * es[i0 * 3 + 2];
      int p1 = atomicAdd(&cnt[i1], 1);
      lists[i1 * TDIM + p1] = t * 2 + 1;
      wt[t * 2 + 1] = v1 * inv * es[i1 * 3 + 2];
    }
    return;
  }

  const int lc = tid & 31;          // 16B source unit within row segment
  const int rowloc = tid >> 5;      // 8 rows per block

  if (b < 768) {  // ---------------- x fp32 -> bf16 ----------------
    const int row = (b - 512) * 8 + rowloc;
    const float* sp = x + (size_t)row * DDIM;
    __hip_bfloat16* dp = xb + (size_t)row * DDIM;
    v4ff r[6];
#pragma unroll
    for (int i = 0; i < 6; ++i) r[i] = *(const v4ff*)(sp + (lc + i * 32) * 4);
#pragma unroll
    for (int i = 0; i < 6; ++i) *(v4bf*)(dp + (lc + i * 32) * 4) = cvt4_f(r[i]);
    return;
  }

  if (b < 5376) {  // ---------------- gate/up pack (linear rows, interleaved dst) ----------------
    const int pb = b - 768;
    const int* isrc = nullptr; const float* fsrc = nullptr;
    __hip_bfloat16* dstT; int T, r8, isint;
    if (pb < 4096) {
      const int e = pb >> 9; T = (pb >> 8) & 1; r8 = pb & 255;
      isrc = (T ? qu : qg) + (size_t)e * IDIM * DDIM;
      dstT = wgub + (size_t)e * (2 * IDIM) * DDIM;
      isint = 1;
    } else {
      const int sb = pb - 4096; T = sb >> 8; r8 = sb & 255;
      fsrc = T ? su : sg;
      dstT = sgub;
      isint = 0;
    }
    const int srcrow = r8 * 8 + rowloc;                       // [0,2048)
    const int rg = ((srcrow >> 4) * 32) + (srcrow & 15) + T * 16;
    __hip_bfloat16* dp = dstT + (size_t)rg * DDIM;

    if (isint) {
      const v4i* sp = (const v4i*)(isrc + (size_t)srcrow * DDIM);
      v4i r[6];
#pragma unroll
      for (int i = 0; i < 6; ++i) r[i] = sp[lc + i * 32];
#pragma unroll
      for (int i = 0; i < 6; ++i) *(v4bf*)(dp + (lc + i * 32) * 4) = cvt4_i(r[i]);
    } else {
      const v4ff* sp = (const v4ff*)(fsrc + (size_t)srcrow * DDIM);
      v4ff r[6];
#pragma unroll
      for (int i = 0; i < 6; ++i) r[i] = sp[lc + i * 32];
#pragma unroll
      for (int i = 0; i < 6; ++i) *(v4bf*)(dp + (lc + i * 32) * 4) = cvt4_f(r[i]);
    }
    return;
  }

  // ---------------- down pack (straight row-major copy) ----------------
  {
    const int pb = b - 5376;
    const int* isrc = nullptr; const float* fsrc = nullptr;
    __hip_bfloat16* dstT; int r8, isint;
    if (pb < 768) {
      const int e = pb / 96; r8 = pb % 96;
      isrc = qd + (size_t)e * DDIM * IDIM;
      dstT = wdb + (size_t)e * DDIM * IDIM;
      isint = 1;
    } else {
      r8 = pb - 768;
      fsrc = sd;
      dstT = sdb;
      isint = 0;
    }
    const int srcrow = r8 * 8 + rowloc;                       // [0,768)
    __hip_bfloat16* dp = dstT + (size_t)srcrow * IDIM;

#pragma unroll
    for (int h2 = 0; h2 < 2; ++h2) {
      if (isint) {
        const v4i* sp = (const v4i*)(isrc + (size_t)srcrow * IDIM);
        v4i r[8];
#pragma unroll
        for (int j = 0; j < 8; ++j) r[j] = sp[lc + (h2 * 8 + j) * 32];
#pragma unroll
        for (int j = 0; j < 8; ++j) *(v4bf*)(dp + (lc + (h2 * 8 + j) * 32) * 4) = cvt4_i(r[j]);
      } else {
        const v4ff* sp = (const v4ff*)(fsrc + (size_t)srcrow * IDIM);
        v4ff r[8];
#pragma unroll
        for (int j = 0; j < 8; ++j) r[j] = sp[lc + (h2 * 8 + j) * 32];
#pragma unroll
        for (int j = 0; j < 8; ++j) *(v4bf*)(dp + (lc + (h2 * 8 + j) * 32) * 4) = cvt4_f(r[j]);
      }
    }
  }
}

// ================= gate+up GEMM, 128x128 tile, N=4096 interleaved =================
// B is ROW-MAJOR bf16; staged like A: per-lane pre-swizzled global col + linear LDS.
// blocks [0,4096): experts (e=b>>9, tm=(b>>5)&15, tn=b&31), gathered rows
// blocks [4096,4608): shared expert, dense rows (h rows 4096+t)
__global__ __launch_bounds__(256, 3)
void gu_gemm_kernel(const __hip_bfloat16* __restrict__ xb,
                    const __hip_bfloat16* __restrict__ wgub, const __hip_bfloat16* __restrict__ sgub,
                    const float* __restrict__ es,
                    const int* __restrict__ cnt, const int* __restrict__ lists,
                    __hip_bfloat16* __restrict__ h)
{
  const int b = blockIdx.x;
  int tm, tn, count;
  const char* bbase;
  const int* listE = nullptr;
  float sgc, suc;
  if (b < 4096) {
    const int e = b >> 9; tm = (b >> 5) & 15; tn = b & 31;
    count = cnt[e];
    if (tm * 128 >= count) return;
    bbase = (const char*)(wgub + (size_t)e * (2 * IDIM) * DDIM);
    listE = lists + e * TDIM;
    sgc = es[e * 3 + 0]; suc = es[e * 3 + 1];
  } else {
    const int b2 = b - 4096; tm = b2 >> 5; tn = b2 & 31;
    count = TDIM;
    bbase = (const char*)sgub;
    sgc = 1.f; suc = 1.f;
  }

  __shared__ __align__(16) char As[16384];
  __shared__ __align__(16) char Bs[16384];

  const int tid = threadIdx.x;
  const int lane = tid & 63;
  const int wid = tid >> 6;
  const int wr = wid >> 1, wc = wid & 1;
  const int lr16 = lane & 15, hk = lane >> 4;

  const int cA = (((lane & 7) ^ (lane >> 3)) << 4);
  const char* aptr[4];
  const char* bptr[4];
#pragma unroll
  for (int p = 0; p < 4; ++p) {
    const int row = p * 32 + wid * 8 + (lane >> 3);
    const int rg = tm * 128 + row;
    int tok;
    if (listE) { const int idx = rg < count ? rg : count - 1; tok = listE[idx] >> 1; }
    else tok = rg;
    aptr[p] = (const char*)xb + (size_t)tok * (DDIM * 2) + cA;
    bptr[p] = bbase + (size_t)(tn * 128 + row) * (DDIM * 2) + cA;
  }

  v4f acc[4][4] = {};

  for (int kt = 0; kt < 12; ++kt) {
#pragma unroll
    for (int p = 0; p < 4; ++p) gload16(aptr[p] + kt * 128, As + wid * 1024 + p * 4096);
#pragma unroll
    for (int p = 0; p < 4; ++p) gload16(bptr[p] + kt * 128, Bs + wid * 1024 + p * 4096);
    __syncthreads();
#pragma unroll
    for (int ks = 0; ks < 2; ++ks) {
      const int colb = ks * 64 + hk * 16;
      v8bf fa[4], fb[4];
#pragma unroll
      for (int m = 0; m < 4; ++m) {
        const int r = wr * 64 + m * 16 + lr16;
        fa[m] = *(const v8bf*)(As + r * 128 + (colb ^ ((r & 7) << 4)));
      }
#pragma unroll
      for (int n = 0; n < 4; ++n) {
        const int r = wc * 64 + n * 16 + lr16;
        fb[n] = *(const v8bf*)(Bs + r * 128 + (colb ^ ((r & 7) << 4)));
      }
#pragma unroll
      for (int n = 0; n < 4; ++n)
#pragma unroll
        for (int m = 0; m < 4; ++m) acc[m][n] = MFMA_B16(fa[m], fb[n], acc[m][n]);
    }
    __syncthreads();
  }

  // epilogue: pairs (2p,2p+1) = (g,u) for i = (tn*4 + wc*2 + p)*16 + lr16
#pragma unroll
  for (int m = 0; m < 4; ++m) {
#pragma unroll
    for (int j = 0; j < 4; ++j) {
      const int rl = wr * 64 + m * 16 + hk * 4 + j;
      const int rg = tm * 128 + rl;
      if (rg >= count) continue;
      const size_t drow = listE ? (size_t)listE[rg] : (size_t)(4096 + rg);
      __hip_bfloat16* dh = h + drow * IDIM + (tn * 4 + wc * 2) * 16 + lr16;
#pragma unroll
      for (int p = 0; p < 2; ++p) {
        const float g = acc[m][2 * p][j] * sgc;
        const float u = acc[m][2 * p + 1][j] * suc;
        dh[p * 16] = __float2bfloat16(g / (1.f + __expf(-g)) * u);
      }
    }
  }
}

// ================= down GEMM, 128x128 tile, K=2048, fp32 partials =================
// blocks [0,768): experts (e=b/96, tm=(b%96)/6, tn=b%6), A = h[slot]; out row = slot
// blocks [768,864): shared expert, A = h[4096+t]; out row = 4096+t
__global__ __launch_bounds__(256, 3)
void down_gemm_kernel(const __hip_bfloat16* __restrict__ h,
                      const __hip_bfloat16* __restrict__ wdb, const __hip_bfloat16* __restrict__ sdb,
                      const float* __restrict__ wt,
                      const int* __restrict__ cnt, const int* __restrict__ lists,
                      float* __restrict__ part)
{
  const int b = blockIdx.x;
  int tm, tn, count;
  const char* bbase;
  const int* listE = nullptr;
  if (b < 768) {
    const int e = b / 96; const int r = b % 96; tm = r / 6; tn = r % 6;
    count = cnt[e];
    if (tm * 128 >= count) return;
    bbase = (const char*)(wdb + (size_t)e * DDIM * IDIM);
    listE = lists + e * TDIM;
  } else {
    const int r = b - 768; tm = r / 6; tn = r % 6;
    count = TDIM;
    bbase = (const char*)sdb;
  }

  __shared__ __align__(16) char As[16384];
  __shared__ __align__(16) char Bs[16384];

  const int tid = threadIdx.x;
  const int lane = tid & 63;
  const int wid = tid >> 6;
  const int wr = wid >> 1, wc = wid & 1;
  const int lr16 = lane & 15, hk = lane >> 4;

  const int cA = (((lane & 7) ^ (lane >> 3)) << 4);
  const char* aptr[4];
  const char* bptr[4];
#pragma unroll
  for (int p = 0; p < 4; ++p) {
    const int row = p * 32 + wid * 8 + (lane >> 3);
    const int rg = tm * 128 + row;
    int srow;
    if (listE) { const int idx = rg < count ? rg : count - 1; srow = listE[idx]; }
    else srow = 4096 + rg;
    aptr[p] = (const char*)h + (size_t)srow * (IDIM * 2) + cA;
    bptr[p] = bbase + (size_t)(tn * 128 + row) * (IDIM * 2) + cA;
  }

  v4f acc[4][4] = {};

  for (int kt = 0; kt < 32; ++kt) {
#pragma unroll
    for (int p = 0; p < 4; ++p) gload16(aptr[p] + kt * 128, As + wid * 1024 + p * 4096);
#pragma unroll
    for (int p = 0; p < 4; ++p) gload16(bptr[p] + kt * 128, Bs + wid * 1024 + p * 4096);
    __syncthreads();
#pragma unroll
    for (int ks = 0; ks < 2; ++ks) {
      const int colb = ks * 64 + hk * 16;
      v8bf fa[4], fb[4];
#pragma unroll
      for (int m = 0; m < 4; ++m) {
        const int r = wr * 64 + m * 16 + lr16;
        fa[m] = *(const v8bf*)(As + r * 128 + (colb ^ ((r & 7) << 4)));
      }
#pragma unroll
      for (int n = 0; n < 4; ++n) {
        const int r = wc * 64 + n * 16 + lr16;
        fb[n] = *(const v8bf*)(Bs + r * 128 + (colb ^ ((r & 7) << 4)));
      }
#pragma unroll
      for (int n = 0; n < 4; ++n)
#pragma unroll
        for (int m = 0; m < 4; ++m) acc[m][n] = MFMA_B16(fa[m], fb[n], acc[m][n]);
    }
    __syncthreads();
  }

#pragma unroll
  for (int m = 0; m < 4; ++m) {
#pragma unroll
    for (int j = 0; j < 4; ++j) {
      const int rl = wr * 64 + m * 16 + hk * 4 + j;
      const int rg = tm * 128 + rl;
      if (rg >= count) continue;
      int orow; float w;
      if (listE) { const int slot = listE[rg]; orow = slot; w = wt[slot]; }  // wt premul sd
      else { orow = 4096 + rg; w = 1.f; }
      float* dst = part + (size_t)orow * DDIM + tn * 128 + wc * 64 + lr16;
#pragma unroll
      for (int n = 0; n < 4; ++n) dst[n * 16] = acc[m][n][j] * w;
    }
  }
}

// ================= combine: out[t] = part[2t] + part[2t+1] + part[4096+t] =================
__global__ __launch_bounds__(256)
void combine_kernel(const float* __restrict__ part, float* __restrict__ out)
{
  const int i4 = blockIdx.x * 256 + threadIdx.x;
  const int i0 = i4 * 4;
  const int t = i0 / DDIM;
  const int d = i0 - t * DDIM;
  float4 a = *(const float4*)(part + (size_t)(2 * t) * DDIM + d);
  float4 bb = *(const float4*)(part + (size_t)(2 * t + 1) * DDIM + d);
  float4 c = *(const float4*)(part + (size_t)(4096 + t) * DDIM + d);
  float4 r;
  r.x = a.x + bb.x + c.x;
  r.y = a.y + bb.y + c.y;
  r.z = a.z + bb.z + c.z;
  r.w = a.w + bb.w + c.w;
  *(float4*)(out + i0) = r;
}

extern "C" void kernel_launch(void* const* d_in, const int* in_sizes, int n_in,
                              void* d_out, int out_size, void* d_ws, size_t ws_size,
                              hipStream_t stream)
{
  const float* x   = (const float*)d_in[0];
  const float* rw  = (const float*)d_in[1];
  const float* swg = (const float*)d_in[2];
  const float* swu = (const float*)d_in[3];
  const float* swd = (const float*)d_in[4];
  const int*   qg  = (const int*)d_in[5];
  const int*   qu  = (const int*)d_in[6];
  const int*   qd  = (const int*)d_in[7];
  const float* es  = (const float*)d_in[8];
  float* out = (float*)d_out;

  char* ws = (char*)d_ws;
  size_t off = 0;
  auto alloc = [&](size_t bytes) { void* p = ws + off; off = (off + bytes + 255) & ~(size_t)255; return p; };
  // ws usage ~= 132 MB
  int*   cnt   = (int*)alloc(NEXP * 4);
  int*   lists = (int*)alloc((size_t)NEXP * TDIM * 4);
  float* wt    = (float*)alloc((size_t)2 * TDIM * 4);
  __hip_bfloat16* xb   = (__hip_bfloat16*)alloc((size_t)TDIM * DDIM * 2);
  __hip_bfloat16* wgub = (__hip_bfloat16*)alloc((size_t)NEXP * 2 * IDIM * DDIM * 2);
  __hip_bfloat16* sgub = (__hip_bfloat16*)alloc((size_t)2 * IDIM * DDIM * 2);
  __hip_bfloat16* wdb  = (__hip_bfloat16*)alloc((size_t)NEXP * DDIM * IDIM * 2);
  __hip_bfloat16* sdb  = (__hip_bfloat16*)alloc((size_t)DDIM * IDIM * 2);
  __hip_bfloat16* h    = (__hip_bfloat16*)alloc((size_t)(4096 + TDIM) * IDIM * 2);
  float* part = (float*)alloc((size_t)(4096 + TDIM) * DDIM * 4);

  hipMemsetAsync(cnt, 0, NEXP * 4, stream);

  pack_all_kernel<<<6240, 256, 0, stream>>>(qg, qu, qd, swg, swu, swd, x, rw, es,
                                            wgub, sgub, wdb, sdb, xb, cnt, lists, wt);
  gu_gemm_kernel<<<4096 + 512, 256, 0, stream>>>(xb, wgub, sgub, es, cnt, lists, h);
  down_gemm_kernel<<<768 + 96, 256, 0, stream>>>(h, wdb, sdb, wt, cnt, lists, part);
  combine_kernel<<<(TDIM * DDIM / 4) / 256, 256, 0, stream>>>(part, out);
}